// Round 1
// baseline (13282.591 us; speedup 1.0000x reference)
//
#include <hip/hip_runtime.h>

// ---------------------------------------------------------------------------
// head3: tensor-conv residual net on MI355X. Round 1: correct fp32 baseline.
//
// Layout for all intermediates: [pix][324] where pix = (b*32+h)*32+w,
// inner tensor flattened p*18+q (a*18+d on outputs). Rows (32 pixels) are
// 10368 contiguous floats -> coalesced float4 staging.
//
// BN is train-mode over (B,H,W)=32768 samples per inner position. Conv
// kernels emit per-block partial (sum, sumsq) via float atomics; the apply
// kernel finalizes scale/shift and applies BN(+PReLU)(+residual) in place.
// Conv biases are skipped: a per-position constant cancels exactly in BN.
// The `_dentity` conv (U1[6], gamma[9]) is dead code in the reference - skipped.
// ---------------------------------------------------------------------------

#define NPOS 324
#define NPIX 32768
#define NELEM 10616832      // NPIX * NPOS
#define NF4   2654208       // NELEM / 4

__device__ __forceinline__ void atomicAddF(float* p, float v) {
    __hip_atomic_fetch_add(p, v, __ATOMIC_RELAXED, __HIP_MEMORY_SCOPE_AGENT);
}

// ---------------------------------------------------------------------------
// conv_f0: x (b,c,p,q,y,w) [8 ch, 16x16 inner] -> out [pix][324], 3x3 taps.
// Block = one (b,h) row, 384 threads. Per (c, y): stage X[pq][ws] (coalesced),
// then per j: Y[a,q,ws] = sum_p U0[a,p] X[p,q,ws]  (phase 1, cooperative),
// acc[w][a,d] += sum_q Y[a,q,w+j-1] V0[q,d]        (phase 2, thread=(a,d)).
// ---------------------------------------------------------------------------
__global__ __launch_bounds__(384, 1) void k_f0(
    const float* __restrict__ x, const float* __restrict__ U0,
    const float* __restrict__ V0, float* __restrict__ out,
    float* __restrict__ stats)
{
    __shared__ float Xs[8192];        // [pq][ws]   pq=p*16+q, stride 32
    __shared__ float Ys[288 * 37];    // [aq][ws]   aq=a*16+q, stride 37 (bank pad)
    __shared__ float UVs[576];        // U0s[288]: a*16+p ; V0s[288]: q*18+d
    const int t = threadIdx.x;
    const int bh = blockIdx.x;
    const int b = bh >> 5, h = bh & 31;
    const int a_ = (t < NPOS) ? t / 18 : 0;
    const int d_ = (t < NPOS) ? t % 18 : 0;

    float acc[32];
#pragma unroll
    for (int w = 0; w < 32; ++w) acc[w] = 0.f;

    for (int c = 0; c < 8; ++c) {
        const float* xb = x + (size_t)(b * 8 + c) * 262144;
        const int ylo = (h == 0) ? 0 : h - 1;
        const int yhi = (h == 31) ? 31 : h + 1;
        for (int y = ylo; y <= yhi; ++y) {
            const int i = y - h + 1;          // tap row index 0..2
            // stage X (safe: all prior readers of Xs are past their phase-1 barrier)
            for (int idx = t; idx < 8192; idx += 384)
                Xs[idx] = xb[(size_t)(idx >> 5) * 1024 + (size_t)y * 32 + (idx & 31)];
            for (int j = 0; j < 3; ++j) {
                const float* Ub = U0 + (c * 9 + i * 3 + j) * 288;
                const float* Vb = V0 + (c * 9 + i * 3 + j) * 288;
                for (int s = t; s < 576; s += 384)
                    UVs[s] = (s < 288) ? Ub[s] : Vb[s - 288];
                __syncthreads();
                float Vreg[16];
                if (t < NPOS) {
#pragma unroll
                    for (int q = 0; q < 16; ++q) Vreg[q] = UVs[288 + q * 18 + d_];
                }
                // phase 1: Y[a,q,ws]
#pragma unroll 4
                for (int k = 0; k < 24; ++k) {
                    const int idx = t + 384 * k;
                    const int ws = idx & 31, aq = idx >> 5;
                    const int a = aq >> 4, q = aq & 15;
                    float s = 0.f;
#pragma unroll
                    for (int p = 0; p < 16; ++p)
                        s += UVs[a * 16 + p] * Xs[(p * 16 + q) * 32 + ws];
                    Ys[aq * 37 + ws] = s;
                }
                __syncthreads();
                // phase 2: accumulate into per-thread (a,d) row accumulators
                if (t < NPOS) {
                    const int wlo = (j == 0) ? 1 : 0;
                    const int whi = (j == 2) ? 30 : 31;
#pragma unroll
                    for (int q = 0; q < 16; ++q) {
                        const float vq = Vreg[q];
                        const int ybase = (a_ * 16 + q) * 37;
#pragma unroll
                        for (int w = 0; w < 32; ++w)
                            if (w >= wlo && w <= whi)
                                acc[w] += Ys[ybase + w + j - 1] * vq;
                    }
                }
                // no barrier needed here: next UV staging doesn't touch Ys, and
                // the next phase-1 write to Ys is behind the staging barrier.
            }
        }
    }
    if (t < NPOS) {
        float s1 = 0.f, s2 = 0.f;
        const size_t base = (size_t)bh * (32 * NPOS);
#pragma unroll
        for (int w = 0; w < 32; ++w) {
            const float v = acc[w];
            out[base + (size_t)w * NPOS + t] = v;
            s1 += v; s2 += v * v;
        }
        atomicAddF(&stats[t], s1);
        atomicAddF(&stats[NPOS + t], s2);
    }
}

// ---------------------------------------------------------------------------
// conv1x1: out = U @ T @ V per pixel. Block = 16 pixels, 384 threads.
// B1: Z[p,d,w] = sum_q T[w,p,q] V[q,d]   (thread = (p,d), V row in regs)
// B2: out[w,a,d] = sum_p U[a,p] Z[p,d,w] (thread = (a,d), U row in regs)
// ---------------------------------------------------------------------------
__global__ __launch_bounds__(384, 1) void k_c1(
    const float* __restrict__ in, const float* __restrict__ U,
    const float* __restrict__ V, float* __restrict__ out,
    float* __restrict__ stats)
{
    __shared__ float Ts[16 * NPOS];
    __shared__ float Zs[NPOS * 18];   // [(p*18+d)][w] stride 18
    const int t = threadIdx.x;
    const size_t base = (size_t)blockIdx.x * (16 * NPOS);
    {
        const float4* src = (const float4*)(in + base);
        float4* dst = (float4*)Ts;
        for (int i = t; i < (16 * NPOS / 4); i += 384) dst[i] = src[i];
    }
    const int e = (t < NPOS) ? t / 18 : 0;   // p in B1, a in B2
    const int d = (t < NPOS) ? t % 18 : 0;
    float Vr[18], Ur[18];
    if (t < NPOS) {
#pragma unroll
        for (int q = 0; q < 18; ++q) Vr[q] = V[q * 18 + d];
#pragma unroll
        for (int p = 0; p < 18; ++p) Ur[p] = U[e * 18 + p];
    }
    __syncthreads();
    if (t < NPOS) {
#pragma unroll
        for (int w = 0; w < 16; ++w) {
            float z = 0.f;
#pragma unroll
            for (int q = 0; q < 18; ++q) z += Ts[w * NPOS + e * 18 + q] * Vr[q];
            Zs[t * 18 + w] = z;
        }
    }
    __syncthreads();
    if (t < NPOS) {
        float s1 = 0.f, s2 = 0.f;
#pragma unroll
        for (int w = 0; w < 16; ++w) {
            float o = 0.f;
#pragma unroll
            for (int p = 0; p < 18; ++p) o += Ur[p] * Zs[(p * 18 + d) * 18 + w];
            out[base + (size_t)w * NPOS + t] = o;
            s1 += o; s2 += o * o;
        }
        atomicAddF(&stats[t], s1);
        atomicAddF(&stats[NPOS + t], s2);
    }
}

// ---------------------------------------------------------------------------
// conv3x3: 3x3 spatial taps, bilinear per tap. Block = one (b,h) row.
// Per source row y: stage T row; per j: Z = T@V3[i,j], acc += U3[i,j]@Z shifted.
// ---------------------------------------------------------------------------
__global__ __launch_bounds__(384, 1) void k_c3(
    const float* __restrict__ in, const float* __restrict__ U3k,
    const float* __restrict__ V3k, float* __restrict__ out,
    float* __restrict__ stats)
{
    __shared__ float Ts[32 * NPOS];   // source row [ws][324]
    __shared__ float Zs[NPOS * 33];   // [(p*18+d)][ws] stride 33 (bank pad)
    const int t = threadIdx.x;
    const int bh = blockIdx.x;
    const int b = bh >> 5, h = bh & 31;
    const int e = (t < NPOS) ? t / 18 : 0;
    const int d = (t < NPOS) ? t % 18 : 0;
    float acc[32];
#pragma unroll
    for (int w = 0; w < 32; ++w) acc[w] = 0.f;

    const int ylo = (h == 0) ? 0 : h - 1;
    const int yhi = (h == 31) ? 31 : h + 1;
    for (int y = ylo; y <= yhi; ++y) {
        const int i = y - h + 1;
        {
            const float4* src = (const float4*)(in + (size_t)(b * 32 + y) * 32 * NPOS);
            float4* dst = (float4*)Ts;
            for (int k = t; k < (32 * NPOS / 4); k += 384) dst[k] = src[k];
        }
        __syncthreads();
        for (int j = 0; j < 3; ++j) {
            if (t < NPOS) {
                float Vr[18];
#pragma unroll
                for (int q = 0; q < 18; ++q) Vr[q] = V3k[(i * 3 + j) * NPOS + q * 18 + d];
                for (int ws = 0; ws < 32; ++ws) {
                    float z = 0.f;
#pragma unroll
                    for (int q = 0; q < 18; ++q) z += Ts[ws * NPOS + e * 18 + q] * Vr[q];
                    Zs[t * 33 + ws] = z;
                }
            }
            __syncthreads();
            if (t < NPOS) {
                float Ur[18];
#pragma unroll
                for (int p = 0; p < 18; ++p) Ur[p] = U3k[(i * 3 + j) * NPOS + e * 18 + p];
                const int wlo = (j == 0) ? 1 : 0;
                const int whi = (j == 2) ? 30 : 31;
#pragma unroll
                for (int w = 0; w < 32; ++w) {
                    if (w >= wlo && w <= whi) {
                        float o = 0.f;
#pragma unroll
                        for (int p = 0; p < 18; ++p)
                            o += Ur[p] * Zs[(p * 18 + d) * 33 + (w + j - 1)];
                        acc[w] += o;
                    }
                }
            }
            __syncthreads();   // Zs overwritten by next j's B1
        }
    }
    if (t < NPOS) {
        float s1 = 0.f, s2 = 0.f;
        const size_t base = (size_t)bh * (32 * NPOS);
#pragma unroll
        for (int w = 0; w < 32; ++w) {
            const float v = acc[w];
            out[base + (size_t)w * NPOS + t] = v;
            s1 += v; s2 += v * v;
        }
        atomicAddF(&stats[t], s1);
        atomicAddF(&stats[NPOS + t], s2);
    }
}

// ---------------------------------------------------------------------------
// BN finalize + apply (+PReLU)(+residual), in place. stats = [sum[324], sumsq[324]].
// ---------------------------------------------------------------------------
__global__ __launch_bounds__(256) void k_apply(
    float* __restrict__ buf, const float* __restrict__ st,
    const float* __restrict__ gamma, const float* __restrict__ beta,
    const float* __restrict__ alpha, const int aidx,
    const float* __restrict__ res)
{
    __shared__ float sc[NPOS], sh[NPOS];
    const int t = threadIdx.x;
    for (int i = t; i < NPOS; i += 256) {
        const float m = st[i] * (1.f / 32768.f);
        float v = st[NPOS + i] * (1.f / 32768.f) - m * m;
        v = fmaxf(v, 0.f);
        const float inv = rsqrtf(v + 1e-5f);
        const float s = gamma[i] * inv;
        sc[i] = s;
        sh[i] = beta[i] - m * s;
    }
    __syncthreads();
    const float a = (aidx >= 0) ? alpha[aidx] : 0.f;
    float4* buf4 = (float4*)buf;
    const float4* res4 = (const float4*)res;
    for (int i4 = blockIdx.x * 256 + t; i4 < NF4; i4 += gridDim.x * 256) {
        const float4 v = buf4[i4];
        const int pos = (i4 * 4) % NPOS;
        float rx = sc[pos + 0] * v.x + sh[pos + 0];
        float ry = sc[pos + 1] * v.y + sh[pos + 1];
        float rz = sc[pos + 2] * v.z + sh[pos + 2];
        float rw = sc[pos + 3] * v.w + sh[pos + 3];
        if (aidx >= 0) {
            rx = rx >= 0.f ? rx : a * rx;
            ry = ry >= 0.f ? ry : a * ry;
            rz = rz >= 0.f ? rz : a * rz;
            rw = rw >= 0.f ? rw : a * rw;
        }
        if (res4) {
            const float4 r = res4[i4];
            rx += r.x; ry += r.y; rz += r.z; rw += r.w;
        }
        float4 o; o.x = rx; o.y = ry; o.z = rz; o.w = rw;
        buf4[i4] = o;
    }
}

// ---------------------------------------------------------------------------
// fcn head: out[b,o,h,w] = sum_pq x31[b,h,w,p,q] Wf[o,p,q] + bf[o]
// ---------------------------------------------------------------------------
__global__ __launch_bounds__(320) void k_head(
    const float* __restrict__ in, const float* __restrict__ Wf,
    const float* __restrict__ bf, float* __restrict__ out)
{
    __shared__ float Ts[32 * 325];    // row, stride 325 (conflict-free for w-lanes)
    const int t = threadIdx.x;
    const int bh = blockIdx.x;
    const int b = bh >> 5, h = bh & 31;
    const float* src = in + (size_t)bh * (32 * NPOS);
    for (int k = t; k < 32 * NPOS; k += 320)
        Ts[(k / NPOS) * 325 + (k % NPOS)] = src[k];
    __syncthreads();
    const int o = t >> 5, w = t & 31;
    float s = bf[o];
    const float* wrow = Wf + o * NPOS;
    const float* trow = Ts + w * 325;
#pragma unroll 4
    for (int k = 0; k < NPOS; ++k) s += trow[k] * wrow[k];
    out[(size_t)((b * 10 + o) * 32 + h) * 32 + w] = s;
}

// ---------------------------------------------------------------------------
extern "C" void kernel_launch(void* const* d_in, const int* in_sizes, int n_in,
                              void* d_out, int out_size, void* d_ws, size_t ws_size,
                              hipStream_t stream)
{
    (void)in_sizes; (void)n_in; (void)out_size; (void)ws_size;
    const float* x  = (const float*)d_in[0];
    const float* U0 = (const float*)d_in[1];
    const float* V0 = (const float*)d_in[2];
    const float* U1 = (const float*)d_in[4];
    const float* V1 = (const float*)d_in[5];
    const float* U3 = (const float*)d_in[7];
    const float* V3 = (const float*)d_in[8];
    const float* Wf = (const float*)d_in[10];
    const float* bf = (const float*)d_in[11];
    const float* g  = (const float*)d_in[12];
    const float* be = (const float*)d_in[13];
    const float* al = (const float*)d_in[14];
    float* out = (float*)d_out;

    float* A  = (float*)d_ws;        // 4 ping-pong tensors + stats
    float* Bu = A  + NELEM;
    float* C  = Bu + NELEM;
    float* D  = C  + NELEM;
    float* st = D  + NELEM;          // 13 * 648 floats

    hipMemsetAsync(st, 0, 13 * 648 * sizeof(float), stream);

    #define ST(k) (st + (k) * 648)
    #define G(k)  (g  + (k) * NPOS)
    #define BE(k) (be + (k) * NPOS)

    // f0
    k_f0<<<1024, 384, 0, stream>>>(x, U0, V0, A, ST(0));
    k_apply<<<1024, 256, 0, stream>>>(A, ST(0), G(0), BE(0), al, 0, nullptr);      // h
    // s1 identity
    k_c1<<<2048, 384, 0, stream>>>(A, U1 + 0 * NPOS, V1 + 0 * NPOS, Bu, ST(1));
    k_apply<<<1024, 256, 0, stream>>>(Bu, ST(1), G(1), BE(1), al, -1, nullptr);    // identity
    // block11
    k_c1<<<2048, 384, 0, stream>>>(A, U1 + 1 * NPOS, V1 + 1 * NPOS, C, ST(2));
    k_apply<<<1024, 256, 0, stream>>>(C, ST(2), G(2), BE(2), al, 1, nullptr);
    k_c3<<<1024, 384, 0, stream>>>(C, U3 + 0 * 2916, V3 + 0 * 2916, D, ST(3));
    k_apply<<<1024, 256, 0, stream>>>(D, ST(3), G(3), BE(3), al, 2, nullptr);
    k_c1<<<2048, 384, 0, stream>>>(D, U1 + 2 * NPOS, V1 + 2 * NPOS, C, ST(4));
    k_apply<<<1024, 256, 0, stream>>>(C, ST(4), G(4), BE(4), al, -1, Bu);          // x11
    // s2 identity
    k_c1<<<2048, 384, 0, stream>>>(C, U1 + 3 * NPOS, V1 + 3 * NPOS, Bu, ST(5));
    k_apply<<<1024, 256, 0, stream>>>(Bu, ST(5), G(5), BE(5), al, -1, nullptr);    // identity2
    // block21
    k_c1<<<2048, 384, 0, stream>>>(C, U1 + 4 * NPOS, V1 + 4 * NPOS, A, ST(6));
    k_apply<<<1024, 256, 0, stream>>>(A, ST(6), G(6), BE(6), al, 3, nullptr);
    k_c3<<<1024, 384, 0, stream>>>(A, U3 + 1 * 2916, V3 + 1 * 2916, D, ST(7));
    k_apply<<<1024, 256, 0, stream>>>(D, ST(7), G(7), BE(7), al, 4, nullptr);
    k_c1<<<2048, 384, 0, stream>>>(D, U1 + 5 * NPOS, V1 + 5 * NPOS, A, ST(8));
    k_apply<<<1024, 256, 0, stream>>>(A, ST(8), G(8), BE(8), al, -1, Bu);          // x21
    // (_dentity with U1[6]/gamma[9] is dead code in the reference -> skipped)
    // block31 (bug-faithful: adds identity2 again)
    k_c1<<<2048, 384, 0, stream>>>(A, U1 + 7 * NPOS, V1 + 7 * NPOS, C, ST(10));
    k_apply<<<1024, 256, 0, stream>>>(C, ST(10), G(10), BE(10), al, 5, nullptr);
    k_c3<<<1024, 384, 0, stream>>>(C, U3 + 2 * 2916, V3 + 2 * 2916, D, ST(11));
    k_apply<<<1024, 256, 0, stream>>>(D, ST(11), G(11), BE(11), al, 6, nullptr);
    k_c1<<<2048, 384, 0, stream>>>(D, U1 + 8 * NPOS, V1 + 8 * NPOS, C, ST(12));
    k_apply<<<1024, 256, 0, stream>>>(C, ST(12), G(12), BE(12), al, -1, Bu);       // x31
    // head
    k_head<<<1024, 320, 0, stream>>>(C, Wf, bf, out);

    #undef ST
    #undef G
    #undef BE
}

// Round 2
// 1914.963 us; speedup vs baseline: 6.9362x; 6.9362x over previous
//
#include <hip/hip_runtime.h>

// ---------------------------------------------------------------------------
// head3 R2: all convs as bf16 MFMA GEMMs.
//   out[pix][n] = sum_taps A_shift[pix][k] @ W_tap[k][n],  n=(a,d) in [0,324)
// W packed on-device as U(x)V outer products in MFMA-B fragment order
// [kg][n][8k] (16B cells). A staged to LDS via global_load_lds(16B) with an
// XOR-kg swizzle (coalesced DMA + bank-balanced ds_read_b128).
// BN stats in fp32 from GEMM accumulators; apply writes fp32 (residual/head)
// + bf16 (next conv input, row stride 384, cols 324..383 zeroed).
// ---------------------------------------------------------------------------

#define NPOS 324
#define NPIX 32768
#define NELEM 10616832      // NPIX*324
#define NF4   2654208       // NELEM/4

typedef __attribute__((ext_vector_type(8))) short short8;     // 8 bf16 = 4 VGPR
typedef __attribute__((ext_vector_type(4))) float f32x4;
typedef __attribute__((ext_vector_type(4))) unsigned short us4;

#define AS1 __attribute__((address_space(1)))
#define AS3 __attribute__((address_space(3)))

__device__ __forceinline__ void atomicAddF(float* p, float v) {
    __hip_atomic_fetch_add(p, v, __ATOMIC_RELAXED, __HIP_MEMORY_SCOPE_AGENT);
}
__device__ __forceinline__ unsigned short f2b(float f) {  // fp32 -> bf16 RNE
    unsigned u = __builtin_bit_cast(unsigned, f);
    u = u + 0x7fffu + ((u >> 16) & 1u);
    return (unsigned short)(u >> 16);
}

// ---------------------------------------------------------------------------
// Unified GEMM-conv. Block = 128 pixels (4 rows of one image), 512 thr (8 waves).
// Wave (wm,wn): wm in {0,1} -> 4 M-tiles; wn in {0..3} -> 6/5/5/5 N-tiles of 336.
// Stage = 64 k-values: A[128][8kg] 16KB + B[8kg][336] 42KB in LDS.
// ---------------------------------------------------------------------------
__global__ __launch_bounds__(512, 2) void k_gconv(
    const unsigned short* __restrict__ in,   // bf16 [NPIX][KS]
    const unsigned short* __restrict__ W,    // bf16 [ntaps][Kper/8][336][8]
    float* __restrict__ out,                 // [NPIX][324]
    float* __restrict__ stats,               // [2][324]
    const unsigned short* __restrict__ zb,   // 4KB zeros
    const int KS, const int Kper, const int ntaps)
{
    __shared__ __align__(16) unsigned short Ab[8192];    // 128 rows x 8 kg x 8
    __shared__ __align__(16) unsigned short Bb[21504];   // 8 kg x 336 n x 8
    __shared__ float slds[672];

    const int tid = threadIdx.x;
    const int wv  = tid >> 6;
    const int L   = tid & 63;
    const int q   = L >> 4;          // quad
    const int l15 = L & 15;
    const int wm  = wv >> 2;
    const int wn  = wv & 3;
    const int ntcnt = (wn == 0) ? 6 : 5;
    const int nt0   = (wn == 0) ? 0 : 6 + 5 * (wn - 1);

    const int blk  = blockIdx.x;
    const int pix0 = blk * 128;
    const int b    = blk >> 3;
    const int h0   = (blk & 7) * 4;

    for (int i = tid; i < 672; i += 512) slds[i] = 0.f;

    const f32x4 fzero = {0.f, 0.f, 0.f, 0.f};
    f32x4 acc[4][6];
#pragma unroll
    for (int i = 0; i < 4; ++i)
#pragma unroll
        for (int j = 0; j < 6; ++j) acc[i][j] = fzero;

    const int nstage = Kper >> 6;
    const int kgper  = Kper >> 3;

    for (int tap = 0; tap < ntaps; ++tap) {
        const int di = (ntaps == 1) ? 0 : (tap / 3 - 1);
        const int dj = (ntaps == 1) ? 0 : (tap % 3 - 1);
        for (int stage = 0; stage < nstage; ++stage) {
            const int kc0 = stage << 6;
            // ---- A stage: 1024 16B chunks, 2 full-wave DMA issues per wave
#pragma unroll
            for (int is = 0; is < 2; ++is) {
                const int c = wv * 128 + is * 64 + L;
                const int m = c >> 3;
                const int g = (c & 7) ^ (m & 7);      // XOR swizzle
                const int rl = m >> 5;
                const int w  = m & 31;
                const int hin = h0 + rl + di;
                const int win = w + dj;
                const unsigned short* gp;
                if ((unsigned)hin < 32u && (unsigned)win < 32u) {
                    const int pixin = (b * 32 + hin) * 32 + win;
                    gp = in + (size_t)pixin * KS + kc0 + g * 8;
                } else {
                    gp = zb + g * 8;
                }
                __builtin_amdgcn_global_load_lds(
                    (AS1 unsigned short*)(uintptr_t)gp,
                    (AS3 unsigned short*)(Ab + (wv * 128 + is * 64) * 8),
                    16, 0, 0);
            }
            // ---- B stage: 2688 16B chunks (wave-aligned: 2688 = 42 waves)
            {
                const unsigned short* wbase =
                    W + (size_t)(tap * kgper + stage * 8) * 336 * 8;
#pragma unroll
                for (int it = 0; it < 6; ++it) {
                    const int cb = it * 512 + tid;
                    if (cb < 2688) {
                        __builtin_amdgcn_global_load_lds(
                            (AS1 unsigned short*)(uintptr_t)(wbase + (size_t)cb * 8),
                            (AS3 unsigned short*)(Bb + (it * 512 + wv * 64) * 8),
                            16, 0, 0);
                    }
                }
            }
            __syncthreads();
            // ---- compute: 2 k-steps of 32
#pragma unroll
            for (int ks = 0; ks < 2; ++ks) {
                const int g = ks * 4 + q;
                short8 a[4];
#pragma unroll
                for (int i = 0; i < 4; ++i) {
                    const int m = (wm * 4 + i) * 16 + l15;
                    const int slot = (m << 3) + (g ^ (m & 7));
                    a[i] = *(const short8*)(Ab + slot * 8);
                }
                short8 bfr[6];
#pragma unroll
                for (int j = 0; j < 6; ++j)
                    if (j < ntcnt)
                        bfr[j] = *(const short8*)(Bb + ((size_t)g * 336 + (nt0 + j) * 16 + l15) * 8);
#pragma unroll
                for (int i = 0; i < 4; ++i)
#pragma unroll
                    for (int j = 0; j < 6; ++j)
                        if (j < ntcnt)
                            acc[i][j] = __builtin_amdgcn_mfma_f32_16x16x32_bf16(
                                a[i], bfr[j], acc[i][j], 0, 0, 0);
            }
            __syncthreads();
        }
    }
    // ---- epilogue: store fp32 + per-column (sum, sumsq)
#pragma unroll
    for (int j = 0; j < 6; ++j) {
        if (j < ntcnt) {
            const int n = (nt0 + j) * 16 + l15;
            float s1 = 0.f, s2 = 0.f;
#pragma unroll
            for (int i = 0; i < 4; ++i) {
#pragma unroll
                for (int r = 0; r < 4; ++r) {
                    const float v = acc[i][j][r];
                    s1 += v; s2 += v * v;
                    const int pix = pix0 + (wm * 4 + i) * 16 + q * 4 + r;
                    if (n < NPOS) out[(size_t)pix * NPOS + n] = v;
                }
            }
            s1 += __shfl_xor(s1, 16); s1 += __shfl_xor(s1, 32);
            s2 += __shfl_xor(s2, 16); s2 += __shfl_xor(s2, 32);
            if (L < 16 && n < NPOS) {
                atomicAdd(&slds[n], s1);
                atomicAdd(&slds[336 + n], s2);
            }
        }
    }
    __syncthreads();
    for (int i = tid; i < 648; i += 512) {
        const int rowi = i / 324, n = i - rowi * 324;
        atomicAddF(&stats[rowi * 324 + n], slds[rowi * 336 + n]);
    }
}

// ---------------------------------------------------------------------------
// x (b,c,p,q,y,w) fp32 -> Xr[(b,y,w)][c*256+p*16+q] bf16. Block=(b,c,y).
// ---------------------------------------------------------------------------
__global__ __launch_bounds__(256) void k_xr(
    const float* __restrict__ x, unsigned short* __restrict__ Xr)
{
    __shared__ float Xs[256 * 33];
    const int t = threadIdx.x;
    const int blk = blockIdx.x;
    const int y = blk & 31;
    const int bc = blk >> 5;
    const int c = bc & 7;
    const int bi = bc >> 3;
    const float* xb = x + (size_t)bc * 262144;
    {
        const int w = t & 31, ph = t >> 5;
        for (int it = 0; it < 32; ++it) {
            const int pq = it * 8 + ph;
            Xs[pq * 33 + w] = xb[(size_t)pq * 1024 + y * 32 + w];
        }
    }
    __syncthreads();
    const int w = t >> 3, gg = t & 7;
    unsigned short* orow = Xr + ((size_t)((bi * 32 + y) * 32 + w)) * 2048 + c * 256;
#pragma unroll
    for (int sub = 0; sub < 4; ++sub) {
        const int pq0 = gg * 32 + sub * 8;
        short8 o;
#pragma unroll
        for (int e = 0; e < 8; ++e) o[e] = (short)f2b(Xs[(pq0 + e) * 33 + w]);
        *(short8*)(orow + pq0) = o;
    }
}

// ---------------------------------------------------------------------------
// W packs: cell offset = linear thread id * 8 (16B per (tap,kg,n) cell)
// ---------------------------------------------------------------------------
__global__ __launch_bounds__(256) void k_pw0(
    const float* __restrict__ U0, const float* __restrict__ V0,
    unsigned short* __restrict__ Wp)
{
    const int t = blockIdx.x * 256 + threadIdx.x;
    if (t >= 9 * 256 * 336) return;
    const int n = t % 336;
    const int kgg = (t / 336) & 255;
    const int tap = t / (336 * 256);
    short8 o = {0, 0, 0, 0, 0, 0, 0, 0};
    if (n < NPOS) {
        const int aa = n / 18, d = n % 18;
#pragma unroll
        for (int j = 0; j < 8; ++j) {
            const int k = kgg * 8 + j;
            const int c = k >> 8, p = (k >> 4) & 15, qq = k & 15;
            const float u = U0[((size_t)(c * 9 + tap) * 18 + aa) * 16 + p];
            const float v = V0[((size_t)(c * 9 + tap) * 16 + qq) * 18 + d];
            o[j] = (short)f2b(u * v);
        }
    }
    *(short8*)(Wp + (size_t)t * 8) = o;
}

__global__ __launch_bounds__(256) void k_pw1(
    const float* __restrict__ U1, const float* __restrict__ V1,
    unsigned short* __restrict__ Wp)
{
    const int t = blockIdx.x * 256 + threadIdx.x;
    if (t >= 9 * 48 * 336) return;
    const int n = t % 336;
    const int kgg = (t / 336) % 48;
    const int cv = t / (336 * 48);
    short8 o = {0, 0, 0, 0, 0, 0, 0, 0};
    if (n < NPOS) {
        const int aa = n / 18, d = n % 18;
#pragma unroll
        for (int j = 0; j < 8; ++j) {
            const int k = kgg * 8 + j;
            if (k < NPOS) {
                const int p = k / 18, qq = k % 18;
                o[j] = (short)f2b(U1[cv * 324 + aa * 18 + p] * V1[cv * 324 + qq * 18 + d]);
            }
        }
    }
    *(short8*)(Wp + (size_t)t * 8) = o;
}

__global__ __launch_bounds__(256) void k_pw3(
    const float* __restrict__ U3, const float* __restrict__ V3,
    unsigned short* __restrict__ Wp)
{
    const int t = blockIdx.x * 256 + threadIdx.x;
    if (t >= 27 * 48 * 336) return;
    const int n = t % 336;
    const int kgg = (t / 336) % 48;
    const int e = t / (336 * 48);    // c3*9 + tap
    short8 o = {0, 0, 0, 0, 0, 0, 0, 0};
    if (n < NPOS) {
        const int aa = n / 18, d = n % 18;
#pragma unroll
        for (int j = 0; j < 8; ++j) {
            const int k = kgg * 8 + j;
            if (k < NPOS) {
                const int p = k / 18, qq = k % 18;
                o[j] = (short)f2b(U3[(size_t)e * 324 + aa * 18 + p] * V3[(size_t)e * 324 + qq * 18 + d]);
            }
        }
    }
    *(short8*)(Wp + (size_t)t * 8) = o;
}

// ---------------------------------------------------------------------------
// BN finalize + apply (+PReLU)(+residual), fp32 in place; optional bf16 copy
// [pix][384] with zeroed pad cols for the next conv.
// ---------------------------------------------------------------------------
__global__ __launch_bounds__(256) void k_apply(
    float* __restrict__ buf, const float* __restrict__ st,
    const float* __restrict__ gamma, const float* __restrict__ beta,
    const float* __restrict__ alpha, const int aidx,
    const float* __restrict__ res,
    unsigned short* __restrict__ bfout)
{
    __shared__ float sc[NPOS], sh[NPOS];
    const int t = threadIdx.x;
    for (int i = t; i < NPOS; i += 256) {
        const float m = st[i] * (1.f / 32768.f);
        float v = st[NPOS + i] * (1.f / 32768.f) - m * m;
        v = fmaxf(v, 0.f);
        const float s = gamma[i] * rsqrtf(v + 1e-5f);
        sc[i] = s;
        sh[i] = beta[i] - m * s;
    }
    __syncthreads();
    const float a = (aidx >= 0) ? alpha[aidx] : 0.f;
    float4* buf4 = (float4*)buf;
    const float4* res4 = (const float4*)res;
    for (int i4 = blockIdx.x * 256 + t; i4 < NF4; i4 += gridDim.x * 256) {
        const float4 v = buf4[i4];
        const int pix = i4 / 81;
        const int pos = (i4 - pix * 81) * 4;
        float rx = sc[pos + 0] * v.x + sh[pos + 0];
        float ry = sc[pos + 1] * v.y + sh[pos + 1];
        float rz = sc[pos + 2] * v.z + sh[pos + 2];
        float rw = sc[pos + 3] * v.w + sh[pos + 3];
        if (aidx >= 0) {
            rx = rx >= 0.f ? rx : a * rx;
            ry = ry >= 0.f ? ry : a * ry;
            rz = rz >= 0.f ? rz : a * rz;
            rw = rw >= 0.f ? rw : a * rw;
        }
        if (res4) {
            const float4 r = res4[i4];
            rx += r.x; ry += r.y; rz += r.z; rw += r.w;
        }
        float4 o; o.x = rx; o.y = ry; o.z = rz; o.w = rw;
        buf4[i4] = o;
        if (bfout) {
            us4 ob = { f2b(rx), f2b(ry), f2b(rz), f2b(rw) };
            *(us4*)(bfout + (size_t)pix * 384 + pos) = ob;
        }
    }
    if (bfout) {  // zero pad cols 324..383
        const us4 z = {0, 0, 0, 0};
        for (int idx = blockIdx.x * 256 + t; idx < NPIX * 15; idx += gridDim.x * 256) {
            const int pix = idx / 15, grp = idx - pix * 15;
            *(us4*)(bfout + (size_t)pix * 384 + 324 + grp * 4) = z;
        }
    }
}

// ---------------------------------------------------------------------------
// fcn head (fp32): out[b,o,h,w] = sum_n x31[pix][n] Wf[o][n] + bf[o]
// ---------------------------------------------------------------------------
__global__ __launch_bounds__(320) void k_head(
    const float* __restrict__ in, const float* __restrict__ Wf,
    const float* __restrict__ bfv, float* __restrict__ out)
{
    __shared__ float Ts[32 * 325];
    const int t = threadIdx.x;
    const int bh = blockIdx.x;
    const int b = bh >> 5, h = bh & 31;
    const float* src = in + (size_t)bh * (32 * NPOS);
    for (int k = t; k < 32 * NPOS; k += 320)
        Ts[(k / NPOS) * 325 + (k % NPOS)] = src[k];
    __syncthreads();
    const int o = t >> 5, w = t & 31;
    float s = bfv[o];
    const float* wrow = Wf + o * NPOS;
    const float* trow = Ts + w * 325;
#pragma unroll 4
    for (int k = 0; k < NPOS; ++k) s += trow[k] * wrow[k];
    out[(size_t)((b * 10 + o) * 32 + h) * 32 + w] = s;
}

// ---------------------------------------------------------------------------
extern "C" void kernel_launch(void* const* d_in, const int* in_sizes, int n_in,
                              void* d_out, int out_size, void* d_ws, size_t ws_size,
                              hipStream_t stream)
{
    (void)in_sizes; (void)n_in; (void)out_size; (void)ws_size;
    const float* x  = (const float*)d_in[0];
    const float* U0 = (const float*)d_in[1];
    const float* V0 = (const float*)d_in[2];
    const float* U1 = (const float*)d_in[4];
    const float* V1 = (const float*)d_in[5];
    const float* U3 = (const float*)d_in[7];
    const float* V3 = (const float*)d_in[8];
    const float* Wf = (const float*)d_in[10];
    const float* bf = (const float*)d_in[11];
    const float* g  = (const float*)d_in[12];
    const float* be = (const float*)d_in[13];
    const float* al = (const float*)d_in[14];
    float* out = (float*)d_out;

    float* A  = (float*)d_ws;
    float* Bu = A  + NELEM;
    float* C  = Bu + NELEM;
    float* D  = C  + NELEM;
    float* st = D  + NELEM;                                  // 13*648 f
    unsigned short* XB  = (unsigned short*)(st + 13 * 648);  // [NPIX][384]
    unsigned short* TB  = XB + (size_t)NPIX * 384;
    unsigned short* Xr  = TB + (size_t)NPIX * 384;           // [NPIX][2048]
    unsigned short* W0p = Xr + (size_t)NPIX * 2048;          // 9*256*336*8
    unsigned short* W1p = W0p + (size_t)9 * 256 * 336 * 8;
    unsigned short* W3p = W1p + (size_t)9 * 48 * 336 * 8;
    unsigned short* ZB  = W3p + (size_t)27 * 48 * 336 * 8;   // 4KB zeros

    hipMemsetAsync(st, 0, 13 * 648 * sizeof(float), stream);
    hipMemsetAsync(ZB, 0, 4096, stream);

    k_xr<<<8192, 256, 0, stream>>>(x, Xr);
    k_pw0<<<(9 * 256 * 336) / 256, 256, 0, stream>>>(U0, V0, W0p);
    k_pw1<<<(9 * 48 * 336 + 255) / 256, 256, 0, stream>>>(U1, V1, W1p);
    k_pw3<<<(27 * 48 * 336 + 255) / 256, 256, 0, stream>>>(U3, V3, W3p);

    #define ST(k) (st + (k) * 648)
    #define G(k)  (g  + (k) * NPOS)
    #define BE(k) (be + (k) * NPOS)
    #define W1C(k) (W1p + (size_t)(k) * 48 * 336 * 8)
    #define W3C(k) (W3p + (size_t)(k) * 9 * 48 * 336 * 8)

    // f0
    k_gconv<<<256, 512, 0, stream>>>(Xr, W0p, A, ST(0), ZB, 2048, 2048, 9);
    k_apply<<<1024, 256, 0, stream>>>(A, ST(0), G(0), BE(0), al, 0, nullptr, XB);        // h
    // s1 identity
    k_gconv<<<256, 512, 0, stream>>>(XB, W1C(0), Bu, ST(1), ZB, 384, 384, 1);
    k_apply<<<1024, 256, 0, stream>>>(Bu, ST(1), G(1), BE(1), al, -1, nullptr, nullptr);
    // block11
    k_gconv<<<256, 512, 0, stream>>>(XB, W1C(1), C, ST(2), ZB, 384, 384, 1);
    k_apply<<<1024, 256, 0, stream>>>(C, ST(2), G(2), BE(2), al, 1, nullptr, TB);
    k_gconv<<<256, 512, 0, stream>>>(TB, W3C(0), D, ST(3), ZB, 384, 384, 9);
    k_apply<<<1024, 256, 0, stream>>>(D, ST(3), G(3), BE(3), al, 2, nullptr, TB);
    k_gconv<<<256, 512, 0, stream>>>(TB, W1C(2), C, ST(4), ZB, 384, 384, 1);
    k_apply<<<1024, 256, 0, stream>>>(C, ST(4), G(4), BE(4), al, -1, Bu, XB);            // x11
    // s2 identity
    k_gconv<<<256, 512, 0, stream>>>(XB, W1C(3), Bu, ST(5), ZB, 384, 384, 1);
    k_apply<<<1024, 256, 0, stream>>>(Bu, ST(5), G(5), BE(5), al, -1, nullptr, nullptr);
    // block21
    k_gconv<<<256, 512, 0, stream>>>(XB, W1C(4), A, ST(6), ZB, 384, 384, 1);
    k_apply<<<1024, 256, 0, stream>>>(A, ST(6), G(6), BE(6), al, 3, nullptr, TB);
    k_gconv<<<256, 512, 0, stream>>>(TB, W3C(1), D, ST(7), ZB, 384, 384, 9);
    k_apply<<<1024, 256, 0, stream>>>(D, ST(7), G(7), BE(7), al, 4, nullptr, TB);
    k_gconv<<<256, 512, 0, stream>>>(TB, W1C(5), A, ST(8), ZB, 384, 384, 1);
    k_apply<<<1024, 256, 0, stream>>>(A, ST(8), G(8), BE(8), al, -1, Bu, XB);            // x21
    // block31 (bug-faithful: reuses s2 identity; U1[6]/gamma[9] dead)
    k_gconv<<<256, 512, 0, stream>>>(XB, W1C(7), C, ST(10), ZB, 384, 384, 1);
    k_apply<<<1024, 256, 0, stream>>>(C, ST(10), G(10), BE(10), al, 5, nullptr, TB);
    k_gconv<<<256, 512, 0, stream>>>(TB, W3C(2), D, ST(11), ZB, 384, 384, 9);
    k_apply<<<1024, 256, 0, stream>>>(D, ST(11), G(11), BE(11), al, 6, nullptr, TB);
    k_gconv<<<256, 512, 0, stream>>>(TB, W1C(8), C, ST(12), ZB, 384, 384, 1);
    k_apply<<<1024, 256, 0, stream>>>(C, ST(12), G(12), BE(12), al, -1, Bu, nullptr);    // x31
    // head
    k_head<<<1024, 320, 0, stream>>>(C, Wf, bf, out);

    #undef ST
    #undef G
    #undef BE
    #undef W1C
    #undef W3C
}

// Round 3
// 1611.223 us; speedup vs baseline: 8.2438x; 1.1885x over previous
//
#include <hip/hip_runtime.h>

// ---------------------------------------------------------------------------
// head3 R3: bf16 MFMA GEMM-convs, restructured for occupancy + halo A-reuse.
//   - gconv: 4 waves, M=64 pixels/block, grid 512 (2 blocks/CU). A staged to
//     LDS (double-buffered, spatial halo shared across 9 taps); B fragments
//     read directly from global (L2) — no B barrier.
//   - all intermediates bf16 [pix][384] (pads zeroed by apply kernels);
//     gconv emits pre-BN bf16 raw + fp32 stats; apply = BN(+PReLU);
//     fused apply = BN(a) + BN(b) for the residual adds.
// ---------------------------------------------------------------------------

#define NPOS 324
#define NPIX 32768

typedef __attribute__((ext_vector_type(8))) short short8;     // 8 bf16
typedef __attribute__((ext_vector_type(8))) unsigned short us8;
typedef __attribute__((ext_vector_type(4))) float f32x4;

#define AS1 __attribute__((address_space(1)))
#define AS3 __attribute__((address_space(3)))

__device__ __forceinline__ void atomicAddF(float* p, float v) {
    __hip_atomic_fetch_add(p, v, __ATOMIC_RELAXED, __HIP_MEMORY_SCOPE_AGENT);
}
__device__ __forceinline__ unsigned short f2b(float f) {  // fp32 -> bf16 RNE
    unsigned u = __builtin_bit_cast(unsigned, f);
    u = u + 0x7fffu + ((u >> 16) & 1u);
    return (unsigned short)(u >> 16);
}
__device__ __forceinline__ float b2f(unsigned short h) {
    unsigned u = ((unsigned)h) << 16;
    return __builtin_bit_cast(float, u);
}

// ---------------------------------------------------------------------------
// gconv: raw[pix][384](bf16, pre-BN, n<324 only) = sum_taps A_shift @ W_tap.
// Block: 64 pixels (2 rows), 256 thr (4 waves: wn 0..3 over 21 n-tiles 6/5/5/5).
// Per k-stage (64 k): A halo (4 rows x 34 cols, XOR-swizzled 16B cells) via
// global_load_lds, double-buffered; 9 (or 1) taps of MFMA with B fragments
// loaded straight from global.
// ---------------------------------------------------------------------------
__global__ __launch_bounds__(256, 2) void k_gconv(
    const unsigned short* __restrict__ in,   // bf16 [NPIX][KS]
    const unsigned short* __restrict__ W,    // bf16 [ntaps][kgper][336][8]
    unsigned short* __restrict__ raw,        // bf16 [NPIX][384] pre-BN out
    float* __restrict__ stats,               // [2][324]
    const unsigned short* __restrict__ zb,   // zeros
    const int KS, const int Kper, const int ntaps)
{
    __shared__ __align__(16) unsigned short Ab[2][1088 * 8];  // halo 136 pix x 64k
    __shared__ float slds[672];

    const int tid = threadIdx.x;
    const int wv  = tid >> 6;
    const int L   = tid & 63;
    const int q   = L >> 4;
    const int l15 = L & 15;
    const int wn  = wv;
    const int ntcnt = (wn == 0) ? 6 : 5;
    const int nt0   = (wn == 0) ? 0 : 6 + 5 * (wn - 1);

    const int blk  = blockIdx.x;
    const int pix0 = blk * 64;
    const int b    = blk >> 4;
    const int h0   = (blk & 15) * 2;
    const bool halo = (ntaps != 1);
    const int nchunk = halo ? 1088 : 512;
    const int nstage = Kper >> 6;
    const int kgper  = Kper >> 3;

    for (int i = tid; i < 672; i += 256) slds[i] = 0.f;

    const f32x4 fzero = {0.f, 0.f, 0.f, 0.f};
    f32x4 acc[4][6];
#pragma unroll
    for (int i = 0; i < 4; ++i)
#pragma unroll
        for (int j = 0; j < 6; ++j) acc[i][j] = fzero;

    // ---- A stage DMA helper (inlined twice)
#define STAGE_A(sbuf, kc0_)                                                    \
    for (int it = 0; it < 5; ++it) {                                           \
        const int c = it * 256 + tid;                                          \
        if (c < nchunk) {                                                      \
            const int pixp = c >> 3;                                           \
            const int g = (c & 7) ^ (pixp & 7);                                \
            const unsigned short* gp;                                          \
            if (halo) {                                                        \
                const int hr = pixp / 34, wc = pixp - hr * 34;                 \
                const int hh = h0 + hr - 1, ww = wc - 1;                       \
                if ((unsigned)hh < 32u && (unsigned)ww < 32u)                  \
                    gp = in + (size_t)((b * 32 + hh) * 32 + ww) * KS + (kc0_) + g * 8; \
                else                                                           \
                    gp = zb + g * 8;                                           \
            } else {                                                           \
                gp = in + (size_t)(pix0 + pixp) * KS + (kc0_) + g * 8;         \
            }                                                                  \
            __builtin_amdgcn_global_load_lds(                                  \
                (AS1 const unsigned short*)(uintptr_t)gp,                      \
                (AS3 unsigned short*)(&Ab[sbuf][0] + (it * 256 + wv * 64) * 8),\
                16, 0, 0);                                                     \
        }                                                                      \
    }

    STAGE_A(0, 0)
    __syncthreads();

    for (int stage = 0; stage < nstage; ++stage) {
        const int cur = stage & 1;
        if (stage + 1 < nstage) {
            STAGE_A(1 - cur, (stage + 1) << 6)
        }
        for (int tap = 0; tap < ntaps; ++tap) {
            const int di = halo ? (tap / 3 - 1) : 0;
            const int dj = halo ? (tap % 3 - 1) : 0;
            const unsigned short* wtap = W + (size_t)(tap * kgper + stage * 8) * 336 * 8;
#pragma unroll
            for (int ks = 0; ks < 2; ++ks) {
                const int g = ks * 4 + q;
                short8 bfr[6];
#pragma unroll
                for (int j = 0; j < 6; ++j)
                    if (j < ntcnt)
                        bfr[j] = *(const short8*)(wtap + ((size_t)g * 336 + (nt0 + j) * 16 + l15) * 8);
                short8 a[4];
#pragma unroll
                for (int i = 0; i < 4; ++i) {
                    const int m = i * 16 + l15;
                    int pixp;
                    if (halo) {
                        const int hr = (m >> 5) + di + 1;
                        const int wc = (m & 31) + dj + 1;
                        pixp = hr * 34 + wc;
                    } else {
                        pixp = m;
                    }
                    const int cell = pixp * 8 + (g ^ (pixp & 7));
                    a[i] = *(const short8*)(&Ab[cur][0] + cell * 8);
                }
#pragma unroll
                for (int i = 0; i < 4; ++i)
#pragma unroll
                    for (int j = 0; j < 6; ++j)
                        if (j < ntcnt)
                            acc[i][j] = __builtin_amdgcn_mfma_f32_16x16x32_bf16(
                                a[i], bfr[j], acc[i][j], 0, 0, 0);
            }
        }
        __syncthreads();
    }
#undef STAGE_A

    // ---- epilogue: bf16 raw store + per-column (sum, sumsq)
#pragma unroll
    for (int j = 0; j < 6; ++j) {
        if (j < ntcnt) {
            const int n = (nt0 + j) * 16 + l15;
            float s1 = 0.f, s2 = 0.f;
#pragma unroll
            for (int i = 0; i < 4; ++i) {
#pragma unroll
                for (int r = 0; r < 4; ++r) {
                    const float v = acc[i][j][r];
                    s1 += v; s2 += v * v;
                    if (n < NPOS)
                        raw[(size_t)(pix0 + i * 16 + q * 4 + r) * 384 + n] = f2b(v);
                }
            }
            s1 += __shfl_xor(s1, 16); s1 += __shfl_xor(s1, 32);
            s2 += __shfl_xor(s2, 16); s2 += __shfl_xor(s2, 32);
            if (L < 16 && n < NPOS) {
                atomicAdd(&slds[n], s1);
                atomicAdd(&slds[336 + n], s2);
            }
        }
    }
    __syncthreads();
    for (int i = tid; i < 648; i += 256) {
        const int rowi = i / 324, n = i - rowi * 324;
        atomicAddF(&stats[rowi * 324 + n], slds[rowi * 336 + n]);
    }
}

// ---------------------------------------------------------------------------
// x (b,c,p,q,y,w) fp32 -> Xr[(b,y,w)][c*256+p*16+q] bf16.
// ---------------------------------------------------------------------------
__global__ __launch_bounds__(256) void k_xr(
    const float* __restrict__ x, unsigned short* __restrict__ Xr)
{
    __shared__ float Xs[256 * 33];
    const int t = threadIdx.x;
    const int blk = blockIdx.x;
    const int y = blk & 31;
    const int bc = blk >> 5;
    const int c = bc & 7;
    const int bi = bc >> 3;
    const float* xb = x + (size_t)bc * 262144;
    {
        const int w = t & 31, ph = t >> 5;
        for (int it = 0; it < 32; ++it) {
            const int pq = it * 8 + ph;
            Xs[pq * 33 + w] = xb[(size_t)pq * 1024 + y * 32 + w];
        }
    }
    __syncthreads();
    const int w = t >> 3, gg = t & 7;
    unsigned short* orow = Xr + ((size_t)((bi * 32 + y) * 32 + w)) * 2048 + c * 256;
#pragma unroll
    for (int sub = 0; sub < 4; ++sub) {
        const int pq0 = gg * 32 + sub * 8;
        short8 o;
#pragma unroll
        for (int e = 0; e < 8; ++e) o[e] = (short)f2b(Xs[(pq0 + e) * 33 + w]);
        *(short8*)(orow + pq0) = o;
    }
}

// ---------------------------------------------------------------------------
// W packs (B-fragment order [tap][kg][n][8k], 16B cells)
// ---------------------------------------------------------------------------
__global__ __launch_bounds__(256) void k_pw0(
    const float* __restrict__ U0, const float* __restrict__ V0,
    unsigned short* __restrict__ Wp)
{
    const int t = blockIdx.x * 256 + threadIdx.x;
    if (t >= 9 * 256 * 336) return;
    const int n = t % 336;
    const int kgg = (t / 336) & 255;
    const int tap = t / (336 * 256);
    short8 o = {0, 0, 0, 0, 0, 0, 0, 0};
    if (n < NPOS) {
        const int aa = n / 18, d = n % 18;
#pragma unroll
        for (int j = 0; j < 8; ++j) {
            const int k = kgg * 8 + j;
            const int c = k >> 8, p = (k >> 4) & 15, qq = k & 15;
            const float u = U0[((size_t)(c * 9 + tap) * 18 + aa) * 16 + p];
            const float v = V0[((size_t)(c * 9 + tap) * 16 + qq) * 18 + d];
            o[j] = (short)f2b(u * v);
        }
    }
    *(short8*)(Wp + (size_t)t * 8) = o;
}

__global__ __launch_bounds__(256) void k_pw1(
    const float* __restrict__ U1, const float* __restrict__ V1,
    unsigned short* __restrict__ Wp)
{
    const int t = blockIdx.x * 256 + threadIdx.x;
    if (t >= 9 * 48 * 336) return;
    const int n = t % 336;
    const int kgg = (t / 336) % 48;
    const int cv = t / (336 * 48);
    short8 o = {0, 0, 0, 0, 0, 0, 0, 0};
    if (n < NPOS) {
        const int aa = n / 18, d = n % 18;
#pragma unroll
        for (int j = 0; j < 8; ++j) {
            const int k = kgg * 8 + j;
            if (k < NPOS) {
                const int p = k / 18, qq = k % 18;
                o[j] = (short)f2b(U1[cv * 324 + aa * 18 + p] * V1[cv * 324 + qq * 18 + d]);
            }
        }
    }
    *(short8*)(Wp + (size_t)t * 8) = o;
}

__global__ __launch_bounds__(256) void k_pw3(
    const float* __restrict__ U3, const float* __restrict__ V3,
    unsigned short* __restrict__ Wp)
{
    const int t = blockIdx.x * 256 + threadIdx.x;
    if (t >= 27 * 48 * 336) return;
    const int n = t % 336;
    const int kgg = (t / 336) % 48;
    const int e = t / (336 * 48);    // c3*9 + tap
    short8 o = {0, 0, 0, 0, 0, 0, 0, 0};
    if (n < NPOS) {
        const int aa = n / 18, d = n % 18;
#pragma unroll
        for (int j = 0; j < 8; ++j) {
            const int k = kgg * 8 + j;
            if (k < NPOS) {
                const int p = k / 18, qq = k % 18;
                o[j] = (short)f2b(U3[(size_t)e * 324 + aa * 18 + p] * V3[(size_t)e * 324 + qq * 18 + d]);
            }
        }
    }
    *(short8*)(Wp + (size_t)t * 8) = o;
}

// ---------------------------------------------------------------------------
// applyA: out(bf16) = PReLU?(sc*raw + sh); pads (cols>=324) zeroed.
// ---------------------------------------------------------------------------
__global__ __launch_bounds__(256) void k_applyA(
    const unsigned short* __restrict__ rawp, const float* __restrict__ st,
    const float* __restrict__ gamma, const float* __restrict__ beta,
    const float* __restrict__ alpha, const int aidx,
    unsigned short* __restrict__ outp)
{
    __shared__ float sc[NPOS], sh[NPOS];
    const int t = threadIdx.x;
    for (int i = t; i < NPOS; i += 256) {
        const float m = st[i] * (1.f / 32768.f);
        float v = st[NPOS + i] * (1.f / 32768.f) - m * m;
        v = fmaxf(v, 0.f);
        const float s = gamma[i] * rsqrtf(v + 1e-5f);
        sc[i] = s;
        sh[i] = beta[i] - m * s;
    }
    __syncthreads();
    const float a = (aidx >= 0) ? alpha[aidx] : 0.f;
    for (int idx = blockIdx.x * 256 + t; idx < NPIX * 48; idx += gridDim.x * 256) {
        const int grp = idx % 48;
        const int c0 = grp * 8;
        us8 o;
        if (c0 < NPOS) {
            const us8 x = *(const us8*)(rawp + (size_t)idx * 8);
#pragma unroll
            for (int e = 0; e < 8; ++e) {
                const int col = c0 + e;
                float r = 0.f;
                if (col < NPOS) {
                    const float v = b2f(x[e]);
                    r = sc[col] * v + sh[col];
                    if (aidx >= 0) r = r >= 0.f ? r : a * r;
                }
                o[e] = f2b(r);
            }
        } else {
            o = (us8){0, 0, 0, 0, 0, 0, 0, 0};
        }
        *(us8*)(outp + (size_t)idx * 8) = o;
    }
}

// ---------------------------------------------------------------------------
// applyR: out(bf16) = (scA*rawA+shA) + (scB*rawB+shB); pads zeroed.
// ---------------------------------------------------------------------------
__global__ __launch_bounds__(256) void k_applyR(
    const unsigned short* __restrict__ rawA, const float* __restrict__ stA,
    const float* __restrict__ gA, const float* __restrict__ bA,
    const unsigned short* __restrict__ rawB, const float* __restrict__ stB,
    const float* __restrict__ gB, const float* __restrict__ bB,
    unsigned short* __restrict__ outp)
{
    __shared__ float scA[NPOS], shA[NPOS], scB[NPOS], shB[NPOS];
    const int t = threadIdx.x;
    for (int i = t; i < NPOS; i += 256) {
        float m = stA[i] * (1.f / 32768.f);
        float v = fmaxf(stA[NPOS + i] * (1.f / 32768.f) - m * m, 0.f);
        float s = gA[i] * rsqrtf(v + 1e-5f);
        scA[i] = s; shA[i] = bA[i] - m * s;
        m = stB[i] * (1.f / 32768.f);
        v = fmaxf(stB[NPOS + i] * (1.f / 32768.f) - m * m, 0.f);
        s = gB[i] * rsqrtf(v + 1e-5f);
        scB[i] = s; shB[i] = bB[i] - m * s;
    }
    __syncthreads();
    for (int idx = blockIdx.x * 256 + t; idx < NPIX * 48; idx += gridDim.x * 256) {
        const int grp = idx % 48;
        const int c0 = grp * 8;
        us8 o;
        if (c0 < NPOS) {
            const us8 xa = *(const us8*)(rawA + (size_t)idx * 8);
            const us8 xb = *(const us8*)(rawB + (size_t)idx * 8);
#pragma unroll
            for (int e = 0; e < 8; ++e) {
                const int col = c0 + e;
                float r = 0.f;
                if (col < NPOS) {
                    r = (scA[col] * b2f(xa[e]) + shA[col])
                      + (scB[col] * b2f(xb[e]) + shB[col]);
                }
                o[e] = f2b(r);
            }
        } else {
            o = (us8){0, 0, 0, 0, 0, 0, 0, 0};
        }
        *(us8*)(outp + (size_t)idx * 8) = o;
    }
}

// ---------------------------------------------------------------------------
// fcn head: out[b,o,h,w] = sum_n x31[pix][n] Wf[o][n] + bf[o]   (x31 bf16)
// ---------------------------------------------------------------------------
__global__ __launch_bounds__(320) void k_head(
    const unsigned short* __restrict__ in, const float* __restrict__ Wf,
    const float* __restrict__ bfv, float* __restrict__ out)
{
    __shared__ float Ts[32 * 325];
    const int t = threadIdx.x;
    const int bh = blockIdx.x;
    const int b = bh >> 5, h = bh & 31;
    const unsigned short* src = in + (size_t)bh * 32 * 384;
    for (int k = t; k < 32 * NPOS; k += 320) {
        const int pl = k / NPOS, col = k - pl * NPOS;
        Ts[pl * 325 + col] = b2f(src[(size_t)pl * 384 + col]);
    }
    __syncthreads();
    const int o = t >> 5, w = t & 31;
    float s = bfv[o];
    const float* wrow = Wf + o * NPOS;
    const float* trow = Ts + w * 325;
#pragma unroll 4
    for (int k = 0; k < NPOS; ++k) s += trow[k] * wrow[k];
    out[(size_t)((b * 10 + o) * 32 + h) * 32 + w] = s;
}

// ---------------------------------------------------------------------------
extern "C" void kernel_launch(void* const* d_in, const int* in_sizes, int n_in,
                              void* d_out, int out_size, void* d_ws, size_t ws_size,
                              hipStream_t stream)
{
    (void)in_sizes; (void)n_in; (void)out_size; (void)ws_size;
    const float* x  = (const float*)d_in[0];
    const float* U0 = (const float*)d_in[1];
    const float* V0 = (const float*)d_in[2];
    const float* U1 = (const float*)d_in[4];
    const float* V1 = (const float*)d_in[5];
    const float* U3 = (const float*)d_in[7];
    const float* V3 = (const float*)d_in[8];
    const float* Wf = (const float*)d_in[10];
    const float* bf = (const float*)d_in[11];
    const float* g  = (const float*)d_in[12];
    const float* be = (const float*)d_in[13];
    const float* al = (const float*)d_in[14];
    float* out = (float*)d_out;

    const size_t NB = (size_t)NPIX * 384;    // bf16 buffer elems
    float* st = (float*)d_ws;                                  // 13*648 f
    unsigned short* ZB  = (unsigned short*)(st + 13 * 648);    // 4KB zeros
    unsigned short* Xr  = ZB + 2048;                           // [NPIX][2048]
    unsigned short* W0p = Xr + (size_t)NPIX * 2048;
    unsigned short* W1p = W0p + (size_t)9 * 256 * 336 * 8;
    unsigned short* W3p = W1p + (size_t)9 * 48 * 336 * 8;
    unsigned short* Rt   = W3p + (size_t)27 * 48 * 336 * 8;
    unsigned short* Rid1 = Rt + NB;
    unsigned short* Rid2 = Rid1 + NB;
    unsigned short* H    = Rid2 + NB;
    unsigned short* T    = H + NB;
    unsigned short* T2   = T + NB;
    unsigned short* X1   = T2 + NB;
    unsigned short* X2   = X1 + NB;
    unsigned short* X3   = X2 + NB;

    hipMemsetAsync(st, 0, 13 * 648 * sizeof(float), stream);
    hipMemsetAsync(ZB, 0, 4096, stream);

    k_xr<<<8192, 256, 0, stream>>>(x, Xr);
    k_pw0<<<(9 * 256 * 336) / 256, 256, 0, stream>>>(U0, V0, W0p);
    k_pw1<<<(9 * 48 * 336 + 255) / 256, 256, 0, stream>>>(U1, V1, W1p);
    k_pw3<<<(27 * 48 * 336 + 255) / 256, 256, 0, stream>>>(U3, V3, W3p);

    #define ST(k) (st + (k) * 648)
    #define G(k)  (g  + (k) * NPOS)
    #define BE(k) (be + (k) * NPOS)
    #define W1C(k) (W1p + (size_t)(k) * 48 * 336 * 8)
    #define W3C(k) (W3p + (size_t)(k) * 9 * 48 * 336 * 8)

    // f0
    k_gconv<<<512, 256, 0, stream>>>(Xr, W0p, Rt, ST(0), ZB, 2048, 2048, 9);
    k_applyA<<<2048, 256, 0, stream>>>(Rt, ST(0), G(0), BE(0), al, 0, H);
    // s1 identity (raw kept) + block11
    k_gconv<<<512, 256, 0, stream>>>(H, W1C(0), Rid1, ST(1), ZB, 384, 384, 1);
    k_gconv<<<512, 256, 0, stream>>>(H, W1C(1), Rt, ST(2), ZB, 384, 384, 1);
    k_applyA<<<2048, 256, 0, stream>>>(Rt, ST(2), G(2), BE(2), al, 1, T);
    k_gconv<<<512, 256, 0, stream>>>(T, W3C(0), Rt, ST(3), ZB, 384, 384, 9);
    k_applyA<<<2048, 256, 0, stream>>>(Rt, ST(3), G(3), BE(3), al, 2, T2);
    k_gconv<<<512, 256, 0, stream>>>(T2, W1C(2), Rt, ST(4), ZB, 384, 384, 1);
    k_applyR<<<2048, 256, 0, stream>>>(Rt, ST(4), G(4), BE(4),
                                       Rid1, ST(1), G(1), BE(1), X1);   // x11
    // s2 identity (raw kept through block31) + block21
    k_gconv<<<512, 256, 0, stream>>>(X1, W1C(3), Rid2, ST(5), ZB, 384, 384, 1);
    k_gconv<<<512, 256, 0, stream>>>(X1, W1C(4), Rt, ST(6), ZB, 384, 384, 1);
    k_applyA<<<2048, 256, 0, stream>>>(Rt, ST(6), G(6), BE(6), al, 3, T);
    k_gconv<<<512, 256, 0, stream>>>(T, W3C(1), Rt, ST(7), ZB, 384, 384, 9);
    k_applyA<<<2048, 256, 0, stream>>>(Rt, ST(7), G(7), BE(7), al, 4, T2);
    k_gconv<<<512, 256, 0, stream>>>(T2, W1C(5), Rt, ST(8), ZB, 384, 384, 1);
    k_applyR<<<2048, 256, 0, stream>>>(Rt, ST(8), G(8), BE(8),
                                       Rid2, ST(5), G(5), BE(5), X2);   // x21
    // block31 (bug-faithful: reuses s2 identity; U1[6]/gamma[9] dead)
    k_gconv<<<512, 256, 0, stream>>>(X2, W1C(7), Rt, ST(10), ZB, 384, 384, 1);
    k_applyA<<<2048, 256, 0, stream>>>(Rt, ST(10), G(10), BE(10), al, 5, T);
    k_gconv<<<512, 256, 0, stream>>>(T, W3C(2), Rt, ST(11), ZB, 384, 384, 9);
    k_applyA<<<2048, 256, 0, stream>>>(Rt, ST(11), G(11), BE(11), al, 6, T2);
    k_gconv<<<512, 256, 0, stream>>>(T2, W1C(8), Rt, ST(12), ZB, 384, 384, 1);
    k_applyR<<<2048, 256, 0, stream>>>(Rt, ST(12), G(12), BE(12),
                                       Rid2, ST(5), G(5), BE(5), X3);   // x31
    // head
    k_head<<<1024, 320, 0, stream>>>(X3, Wf, bf, out);

    #undef ST
    #undef G
    #undef BE
    #undef W1C
    #undef W3C
}